// Round 4
// baseline (872.293 us; speedup 1.0000x reference)
//
#include <hip/hip_runtime.h>
#include <hip/hip_bf16.h>

// ---------------------------------------------------------------------------
// CFGSubASTExpressionCombiner: enc->bf16, counting-sort by segment,
// Q/K/V projections (bf16 MFMA, full-N 128x256 tiles, gather rows once),
// CSR segment softmax+pool (no atomics), output GEMM.
// D = 256, H = 8, HD = 32, OUT = 256.
// NOTE: no hipMemsetAsync in the graph — small in-graph fills cost ~235us each
// (round-3 rocprof: fillBufferAligned 390KB @ 1.8 GB/s). Zeroing is done by a
// custom kernel; scatter cursors are initialized by the scan kernel itself.
// ---------------------------------------------------------------------------

typedef __attribute__((ext_vector_type(8))) short bf16x8;
typedef __attribute__((ext_vector_type(4))) float f32x4;

#define DEV __device__ __forceinline__

DEV float bf2f(unsigned short u) {
    union { unsigned int i; float f; } x;
    x.i = ((unsigned int)u) << 16;
    return x.f;
}

DEV unsigned short f2bf(float f) {
    union { float f; unsigned int i; } x;
    x.f = f;
    unsigned int i = x.i;
    unsigned int r = 0x7fffu + ((i >> 16) & 1u);   // round-to-nearest-even
    return (unsigned short)((i + r) >> 16);
}

// ---------------------------------------------------------------------------
// enc fp32 -> bf16 (grid-stride, float4 in / ushort4 out)
// ---------------------------------------------------------------------------
__global__ __launch_bounds__(256) void conv_enc(const float* __restrict__ in,
                                                unsigned short* __restrict__ out,
                                                int n4) {
    const int stride = gridDim.x * 256;
    for (int i = blockIdx.x * 256 + threadIdx.x; i < n4; i += stride) {
        const float4 v = ((const float4*)in)[i];
        ushort4 o;
        o.x = f2bf(v.x); o.y = f2bf(v.y); o.z = f2bf(v.z); o.w = f2bf(v.w);
        ((ushort4*)out)[i] = o;
    }
}

// ---------------------------------------------------------------------------
// Weight prep: transpose fp32 [K][N] weights into bf16 [N][K] layout.
// ---------------------------------------------------------------------------
__global__ void convert_weights(const float* __restrict__ Wq,
                                const float* __restrict__ Wk,
                                const float* __restrict__ Wv,
                                const float* __restrict__ Wo,
                                unsigned short* __restrict__ Wtq,
                                unsigned short* __restrict__ Wtk,
                                unsigned short* __restrict__ Wtv,
                                unsigned short* __restrict__ Wto) {
    int t = blockIdx.x * 256 + threadIdx.x;
    if (t >= 4 * 65536) return;
    int which = t >> 16;
    int u = t & 65535;
    int n = u >> 8, k = u & 255;
    const float* W = which == 0 ? Wq : which == 1 ? Wk : which == 2 ? Wv : Wo;
    unsigned short* Wt = which == 0 ? Wtq : which == 1 ? Wtk : which == 2 ? Wtv : Wto;
    Wt[u] = f2bf(W[k * 256 + n]);
}

// ---------------------------------------------------------------------------
// Counting sort of mapping entries by segment id.
// ---------------------------------------------------------------------------
__global__ void zero_kernel(int* __restrict__ p, int n) {
    int i = blockIdx.x * 256 + threadIdx.x;
    if (i < n) p[i] = 0;
}

__global__ void hist_kernel(const int* __restrict__ map_val,
                            int* __restrict__ counts, int M) {
    int m = blockIdx.x * 256 + threadIdx.x;
    if (m < M) atomicAdd(&counts[map_val[m]], 1);
}

// Single-block exclusive scan over counts[S] -> offsets[S+1], cursor[S].
__global__ __launch_bounds__(1024) void scan_kernel(const int* __restrict__ counts,
                                                    int* __restrict__ offsets,
                                                    int* __restrict__ cursor, int S) {
    __shared__ int part[1024];
    const int t = threadIdx.x;
    const int chunk = (S + 1023) / 1024;
    const int lo = t * chunk;
    const int hi = min(lo + chunk, S);
    int sum = 0;
    for (int i = lo; i < hi; ++i) sum += counts[i];
    part[t] = sum;
    __syncthreads();
    for (int d = 1; d < 1024; d <<= 1) {
        int v = (t >= d) ? part[t - d] : 0;
        __syncthreads();
        part[t] += v;
        __syncthreads();
    }
    int run = (t > 0) ? part[t - 1] : 0;
    for (int i = lo; i < hi; ++i) {
        offsets[i] = run;
        cursor[i] = run;
        run += counts[i];
    }
    if (t == 1023) offsets[S] = part[1023];
}

__global__ void scatter_kernel(const int* __restrict__ map_key,
                               const int* __restrict__ map_val,
                               int* __restrict__ cursor,
                               int* __restrict__ sorted_src, int M) {
    int m = blockIdx.x * 256 + threadIdx.x;
    if (m >= M) return;
    int seg = map_val[m];
    int pos = atomicAdd(&cursor[seg], 1);
    sorted_src[pos] = map_key[m];
}

// ---------------------------------------------------------------------------
// GEMM: Out[dst(r)][colOff+n] = sum_k A[src(r)][k] * Wt[n][k] + bias[n]
// A bf16 [*][256], Wt bf16 [256][256]. Tile 128(M) x 256(N), K=256 in 4x64.
// 512 threads = 8 waves, wave (wm,wn) in 2x4 grid owns a 64x64 quadrant.
// A rows fetched once per GEMM; next k-tile A prefetched into registers.
// ---------------------------------------------------------------------------
template <bool GATHER, bool SCATTER, bool OUT_F32>
__global__ __launch_bounds__(512) void gemm256(
    const unsigned short* __restrict__ A,
    const int* __restrict__ srcIdx,
    const int* __restrict__ dstIdx,
    const unsigned short* __restrict__ Wt,
    const float* __restrict__ bias,
    void* __restrict__ Out,
    int nrows, int ldo, int colOff) {
    __shared__ unsigned short Alds[128][72];
    __shared__ unsigned short Blds[256][72];

    const int tm = blockIdx.x;
    const int tid = threadIdx.x;
    const int wave = tid >> 6, lane = tid & 63;
    const int wm = wave >> 2, wn = wave & 3;

    const int c8 = (tid & 7) * 8;
    const int rb = tid >> 3;   // 0..63

    long src0, src1;
    {
        const int gr0 = tm * 128 + rb;
        const int gr1 = gr0 + 64;
        src0 = (gr0 < nrows) ? (GATHER ? (long)srcIdx[gr0] : (long)gr0) : 0;
        src1 = (gr1 < nrows) ? (GATHER ? (long)srcIdx[gr1] : (long)gr1) : 0;
    }
    const unsigned short* arow0 = A + src0 * 256 + c8;
    const unsigned short* arow1 = A + src1 * 256 + c8;

    f32x4 acc[4][4] = {};

    uint4 a0 = *(const uint4*)(arow0);
    uint4 a1 = *(const uint4*)(arow1);

    for (int kt = 0; kt < 4; ++kt) {
        const int k0 = kt * 64;

        // stage current k-tile
        *(uint4*)(&Alds[rb][c8])       = a0;
        *(uint4*)(&Alds[rb + 64][c8])  = a1;
        *(uint4*)(&Blds[rb][c8])       = *(const uint4*)(Wt + (long)(rb)       * 256 + k0 + c8);
        *(uint4*)(&Blds[rb + 64][c8])  = *(const uint4*)(Wt + (long)(rb + 64)  * 256 + k0 + c8);
        *(uint4*)(&Blds[rb + 128][c8]) = *(const uint4*)(Wt + (long)(rb + 128) * 256 + k0 + c8);
        *(uint4*)(&Blds[rb + 192][c8]) = *(const uint4*)(Wt + (long)(rb + 192) * 256 + k0 + c8);

        __syncthreads();

        // prefetch next k-tile of A while MFMA runs
        if (kt < 3) {
            a0 = *(const uint4*)(arow0 + k0 + 64);
            a1 = *(const uint4*)(arow1 + k0 + 64);
        }

#pragma unroll
        for (int ks = 0; ks < 2; ++ks) {
            const int kb = ks * 32 + (lane >> 4) * 8;
            bf16x8 a[4], b[4];
#pragma unroll
            for (int i = 0; i < 4; ++i)
                a[i] = *(const bf16x8*)(&Alds[wm * 64 + i * 16 + (lane & 15)][kb]);
#pragma unroll
            for (int j = 0; j < 4; ++j)
                b[j] = *(const bf16x8*)(&Blds[wn * 64 + j * 16 + (lane & 15)][kb]);
#pragma unroll
            for (int i = 0; i < 4; ++i)
#pragma unroll
                for (int j = 0; j < 4; ++j)
                    acc[i][j] = __builtin_amdgcn_mfma_f32_16x16x32_bf16(a[i], b[j], acc[i][j], 0, 0, 0);
        }

        __syncthreads();
    }

    // ---- epilogue ----
#pragma unroll
    for (int i = 0; i < 4; ++i) {
#pragma unroll
        for (int j = 0; j < 4; ++j) {
            const int lcol = wn * 64 + j * 16 + (lane & 15);
            const float bs = bias[lcol];
            const int col = colOff + lcol;
#pragma unroll
            for (int rj = 0; rj < 4; ++rj) {
                const int row = tm * 128 + wm * 64 + i * 16 + (lane >> 4) * 4 + rj;
                if (row < nrows) {
                    long drow = SCATTER ? (long)dstIdx[row] : (long)row;
                    float val = acc[i][j][rj] + bs;
                    if constexpr (OUT_F32)
                        ((float*)Out)[drow * ldo + col] = val;
                    else
                        ((unsigned short*)Out)[drow * ldo + col] = f2bf(val);
                }
            }
        }
    }
}

// ---------------------------------------------------------------------------
// CSR pooling: one wave per segment s; kv rows for s are [offsets[s],offsets[s+1]).
// score_h = <k[e,h,:], q[s,h,:]>*scale ; ew = exp(score) (shift-free; |score|<~1)
// pooled[s] = sum ew*v / sum ew, written bf16 IN PLACE over q[s].
// ---------------------------------------------------------------------------
__global__ __launch_bounds__(256) void pool_csr_kernel(
    unsigned short* __restrict__ q,          // bf16 [S][256] (in: q, out: pooled)
    const unsigned short* __restrict__ kv,   // bf16 [Msorted][512] (k | v)
    const int* __restrict__ offsets,         // [S+1]
    int S) {
    const int s = blockIdx.x * 4 + (threadIdx.x >> 6);
    if (s >= S) return;
    const int lane = threadIdx.x & 63;
    const int beg = offsets[s];
    const int end = offsets[s + 1];

    const ushort4 qv = *(const ushort4*)(q + (long)s * 256 + lane * 4);
    const float q0 = bf2f(qv.x), q1 = bf2f(qv.y), q2 = bf2f(qv.z), q3 = bf2f(qv.w);

    float a0 = 0.f, a1 = 0.f, a2 = 0.f, a3 = 0.f, denom = 0.f;

    for (int e = beg; e < end; ++e) {
        const ushort4 kk = *(const ushort4*)(kv + (long)e * 512 + lane * 4);
        const ushort4 vv = *(const ushort4*)(kv + (long)e * 512 + 256 + lane * 4);
        float p = q0 * bf2f(kk.x) + q1 * bf2f(kk.y) + q2 * bf2f(kk.z) + q3 * bf2f(kk.w);
        p += __shfl_xor(p, 1);
        p += __shfl_xor(p, 2);
        p += __shfl_xor(p, 4);   // 8-lane head group holds the head dot
        const float ew = expf(p * 0.17677669529663687f);  // 1/sqrt(32)
        a0 += ew * bf2f(vv.x);
        a1 += ew * bf2f(vv.y);
        a2 += ew * bf2f(vv.z);
        a3 += ew * bf2f(vv.w);
        denom += ew;
    }

    const float w = 1.0f / fmaxf(denom, 1e-9f);
    ushort4 o;
    o.x = f2bf(a0 * w);
    o.y = f2bf(a1 * w);
    o.z = f2bf(a2 * w);
    o.w = f2bf(a3 * w);
    *(ushort4*)(q + (long)s * 256 + lane * 4) = o;
}

// ---------------------------------------------------------------------------
extern "C" void kernel_launch(void* const* d_in, const int* in_sizes, int n_in,
                              void* d_out, int out_size, void* d_ws, size_t ws_size,
                              hipStream_t stream) {
    const float* enc  = (const float*)d_in[0];
    const float* W_q  = (const float*)d_in[1];
    const float* b_q  = (const float*)d_in[2];
    const float* W_k  = (const float*)d_in[3];
    const float* b_k  = (const float*)d_in[4];
    const float* W_v  = (const float*)d_in[5];
    const float* b_v  = (const float*)d_in[6];
    const float* W_o  = (const float*)d_in[7];
    const float* b_o  = (const float*)d_in[8];
    const int* map_key = (const int*)d_in[9];    // [M] ast idx
    const int* map_val = (const int*)d_in[10];   // [M] cfg idx (segment id)
    const int* pdg_key = (const int*)d_in[11];   // [S] dst rows (bijection)
    const int* pdg_val = (const int*)d_in[12];   // [S] src ast rows

    const int M = in_sizes[9];
    const int S = in_sizes[11];
    const int NAST = in_sizes[0] / 256;

    char* ws = (char*)d_ws;
    size_t off = 0;
    auto alloc = [&](size_t bytes) -> char* {
        char* p = ws + off;
        off += (bytes + 255) & ~(size_t)255;
        return p;
    };

    unsigned short* Wt_q  = (unsigned short*)alloc(256 * 256 * 2);
    unsigned short* Wt_k  = (unsigned short*)alloc(256 * 256 * 2);
    unsigned short* Wt_v  = (unsigned short*)alloc(256 * 256 * 2);
    unsigned short* Wt_o  = (unsigned short*)alloc(256 * 256 * 2);
    int*            counts  = (int*)alloc((size_t)S * 4);
    int*            cursor  = (int*)alloc((size_t)S * 4);
    int*            offsets = (int*)alloc((size_t)(S + 1) * 4);
    int*            sorted_src = (int*)alloc((size_t)M * 4);
    unsigned short* enc16 = (unsigned short*)alloc((size_t)NAST * 256 * 2);
    unsigned short* qbuf  = (unsigned short*)alloc((size_t)S * 256 * 2);  // q, then pooled
    unsigned short* kvbuf = (unsigned short*)alloc((size_t)M * 512 * 2);

    // zero counts with a plain kernel (NOT hipMemsetAsync: in-graph small
    // fills cost ~235us each on this stack)
    zero_kernel<<<(S + 255) / 256, 256, 0, stream>>>(counts, S);

    conv_enc<<<2048, 256, 0, stream>>>(enc, enc16, NAST * 64);

    convert_weights<<<1024, 256, 0, stream>>>(W_q, W_k, W_v, W_o, Wt_q, Wt_k, Wt_v, Wt_o);

    // counting sort of mapping entries by segment
    hist_kernel<<<(M + 255) / 256, 256, 0, stream>>>(map_val, counts, M);
    scan_kernel<<<1, 1024, 0, stream>>>(counts, offsets, cursor, S);
    scatter_kernel<<<(M + 255) / 256, 256, 0, stream>>>(
        map_key, map_val, cursor, sorted_src, M);

    // Q projection: q[pdg_key[i]] = enc16[pdg_val[i]] @ W_q + b_q
    gemm256<true, true, false><<<(S + 127) / 128, 512, 0, stream>>>(
        enc16, pdg_val, pdg_key, Wt_q, b_q, qbuf, S, 256, 0);

    // K projection into kv[:, 0:256]
    gemm256<true, false, false><<<(M + 127) / 128, 512, 0, stream>>>(
        enc16, sorted_src, nullptr, Wt_k, b_k, kvbuf, M, 512, 0);

    // V projection into kv[:, 256:512]
    gemm256<true, false, false><<<(M + 127) / 128, 512, 0, stream>>>(
        enc16, sorted_src, nullptr, Wt_v, b_v, kvbuf, M, 512, 256);

    // CSR segment softmax + pooling; pooled overwrites qbuf
    pool_csr_kernel<<<(S + 3) / 4, 256, 0, stream>>>(qbuf, kvbuf, offsets, S);

    // output projection to d_out (fp32)
    gemm256<false, false, true><<<(S + 127) / 128, 512, 0, stream>>>(
        qbuf, nullptr, nullptr, Wt_o, b_o, d_out, S, 256, 0);
}

// Round 5
// 654.765 us; speedup vs baseline: 1.3322x; 1.3322x over previous
//
#include <hip/hip_runtime.h>
#include <hip/hip_bf16.h>

// ---------------------------------------------------------------------------
// CFGSubASTExpressionCombiner: enc->bf16, counting-sort by segment,
// Q/K/V projections (bf16 MFMA, full-N 128x256 tiles, gather rows once),
// CSR segment softmax+pool (no atomics), output GEMM.
// D = 256, H = 8, HD = 32, OUT = 256.
// NOTES:
//  - no hipMemsetAsync in the graph (in-graph small fills ~235us each, r3).
//  - scan is 3-phase multi-block (single-block scan was 233us on 1 CU, r4).
// ---------------------------------------------------------------------------

typedef __attribute__((ext_vector_type(8))) short bf16x8;
typedef __attribute__((ext_vector_type(4))) float f32x4;

#define DEV __device__ __forceinline__

DEV float bf2f(unsigned short u) {
    union { unsigned int i; float f; } x;
    x.i = ((unsigned int)u) << 16;
    return x.f;
}

DEV unsigned short f2bf(float f) {
    union { float f; unsigned int i; } x;
    x.f = f;
    unsigned int i = x.i;
    unsigned int r = 0x7fffu + ((i >> 16) & 1u);   // round-to-nearest-even
    return (unsigned short)((i + r) >> 16);
}

// ---------------------------------------------------------------------------
// enc fp32 -> bf16 (grid-stride, float4 in / ushort4 out)
// ---------------------------------------------------------------------------
__global__ __launch_bounds__(256) void conv_enc(const float* __restrict__ in,
                                                unsigned short* __restrict__ out,
                                                int n4) {
    const int stride = gridDim.x * 256;
    for (int i = blockIdx.x * 256 + threadIdx.x; i < n4; i += stride) {
        const float4 v = ((const float4*)in)[i];
        ushort4 o;
        o.x = f2bf(v.x); o.y = f2bf(v.y); o.z = f2bf(v.z); o.w = f2bf(v.w);
        ((ushort4*)out)[i] = o;
    }
}

// ---------------------------------------------------------------------------
// Weight prep: transpose fp32 [K][N] weights into bf16 [N][K] layout.
// ---------------------------------------------------------------------------
__global__ void convert_weights(const float* __restrict__ Wq,
                                const float* __restrict__ Wk,
                                const float* __restrict__ Wv,
                                const float* __restrict__ Wo,
                                unsigned short* __restrict__ Wtq,
                                unsigned short* __restrict__ Wtk,
                                unsigned short* __restrict__ Wtv,
                                unsigned short* __restrict__ Wto) {
    int t = blockIdx.x * 256 + threadIdx.x;
    if (t >= 4 * 65536) return;
    int which = t >> 16;
    int u = t & 65535;
    int n = u >> 8, k = u & 255;
    const float* W = which == 0 ? Wq : which == 1 ? Wk : which == 2 ? Wv : Wo;
    unsigned short* Wt = which == 0 ? Wtq : which == 1 ? Wtk : which == 2 ? Wtv : Wto;
    Wt[u] = f2bf(W[k * 256 + n]);
}

// ---------------------------------------------------------------------------
// Counting sort of mapping entries by segment id.
// ---------------------------------------------------------------------------
__global__ void zero_kernel(int* __restrict__ p, int n) {
    int i = blockIdx.x * 256 + threadIdx.x;
    if (i < n) p[i] = 0;
}

__global__ void hist_kernel(const int* __restrict__ map_val,
                            int* __restrict__ counts, int M) {
    int m = blockIdx.x * 256 + threadIdx.x;
    if (m < M) atomicAdd(&counts[map_val[m]], 1);
}

// ---- 3-phase exclusive scan over counts[S] -> offsets[S+1], cursor[S] ----
// Phase 1: per-block (256 elems) sums.
__global__ __launch_bounds__(256) void scan_p1(const int* __restrict__ counts,
                                               int* __restrict__ bsum, int S) {
    const int i = blockIdx.x * 256 + threadIdx.x;
    int v = (i < S) ? counts[i] : 0;
#pragma unroll
    for (int d = 1; d < 64; d <<= 1) v += __shfl_xor(v, d);
    __shared__ int ws[4];
    if ((threadIdx.x & 63) == 0) ws[threadIdx.x >> 6] = v;
    __syncthreads();
    if (threadIdx.x == 0) bsum[blockIdx.x] = ws[0] + ws[1] + ws[2] + ws[3];
}

// Phase 2: single block scans nb blocksums (chunked, nb ~ a few hundred);
// writes exclusive block prefixes and offsets[S] = total.
__global__ __launch_bounds__(256) void scan_p2(const int* __restrict__ bsum,
                                               int* __restrict__ bpref,
                                               int* __restrict__ offsets,
                                               int nb, int S) {
    __shared__ int part[256];
    const int t = threadIdx.x;
    const int chunk = (nb + 255) / 256;
    const int lo = t * chunk;
    const int hi = min(lo + chunk, nb);
    int sum = 0;
    for (int i = lo; i < hi; ++i) sum += bsum[i];
    part[t] = sum;
    __syncthreads();
    for (int d = 1; d < 256; d <<= 1) {
        int v = (t >= d) ? part[t - d] : 0;
        __syncthreads();
        part[t] += v;
        __syncthreads();
    }
    int run = (t > 0) ? part[t - 1] : 0;
    for (int i = lo; i < hi; ++i) {
        bpref[i] = run;
        run += bsum[i];
    }
    if (t == 255) offsets[S] = part[255];
}

// Phase 3: in-block exclusive scan + block prefix -> offsets[i], cursor[i].
__global__ __launch_bounds__(256) void scan_p3(const int* __restrict__ counts,
                                               const int* __restrict__ bpref,
                                               int* __restrict__ offsets,
                                               int* __restrict__ cursor, int S) {
    __shared__ int sh[256];
    const int t = threadIdx.x;
    const int i = blockIdx.x * 256 + t;
    const int v = (i < S) ? counts[i] : 0;
    sh[t] = v;
    __syncthreads();
    for (int d = 1; d < 256; d <<= 1) {
        int u = (t >= d) ? sh[t - d] : 0;
        __syncthreads();
        sh[t] += u;
        __syncthreads();
    }
    if (i < S) {
        const int e = sh[t] - v + bpref[blockIdx.x];
        offsets[i] = e;
        cursor[i] = e;
    }
}

__global__ void scatter_kernel(const int* __restrict__ map_key,
                               const int* __restrict__ map_val,
                               int* __restrict__ cursor,
                               int* __restrict__ sorted_src, int M) {
    int m = blockIdx.x * 256 + threadIdx.x;
    if (m >= M) return;
    int seg = map_val[m];
    int pos = atomicAdd(&cursor[seg], 1);
    sorted_src[pos] = map_key[m];
}

// ---------------------------------------------------------------------------
// GEMM: Out[dst(r)][colOff+n] = sum_k A[src(r)][k] * Wt[n][k] + bias[n]
// A bf16 [*][256], Wt bf16 [256][256]. Tile 128(M) x 256(N), K=256 in 4x64.
// 512 threads = 8 waves, wave (wm,wn) in 2x4 grid owns a 64x64 quadrant.
// ---------------------------------------------------------------------------
template <bool GATHER, bool SCATTER, bool OUT_F32>
__global__ __launch_bounds__(512) void gemm256(
    const unsigned short* __restrict__ A,
    const int* __restrict__ srcIdx,
    const int* __restrict__ dstIdx,
    const unsigned short* __restrict__ Wt,
    const float* __restrict__ bias,
    void* __restrict__ Out,
    int nrows, int ldo, int colOff) {
    __shared__ unsigned short Alds[128][72];
    __shared__ unsigned short Blds[256][72];

    const int tm = blockIdx.x;
    const int tid = threadIdx.x;
    const int wave = tid >> 6, lane = tid & 63;
    const int wm = wave >> 2, wn = wave & 3;

    const int c8 = (tid & 7) * 8;
    const int rb = tid >> 3;   // 0..63

    long src0, src1;
    {
        const int gr0 = tm * 128 + rb;
        const int gr1 = gr0 + 64;
        src0 = (gr0 < nrows) ? (GATHER ? (long)srcIdx[gr0] : (long)gr0) : 0;
        src1 = (gr1 < nrows) ? (GATHER ? (long)srcIdx[gr1] : (long)gr1) : 0;
    }
    const unsigned short* arow0 = A + src0 * 256 + c8;
    const unsigned short* arow1 = A + src1 * 256 + c8;

    f32x4 acc[4][4] = {};

    uint4 a0 = *(const uint4*)(arow0);
    uint4 a1 = *(const uint4*)(arow1);

    for (int kt = 0; kt < 4; ++kt) {
        const int k0 = kt * 64;

        // stage current k-tile
        *(uint4*)(&Alds[rb][c8])       = a0;
        *(uint4*)(&Alds[rb + 64][c8])  = a1;
        *(uint4*)(&Blds[rb][c8])       = *(const uint4*)(Wt + (long)(rb)       * 256 + k0 + c8);
        *(uint4*)(&Blds[rb + 64][c8])  = *(const uint4*)(Wt + (long)(rb + 64)  * 256 + k0 + c8);
        *(uint4*)(&Blds[rb + 128][c8]) = *(const uint4*)(Wt + (long)(rb + 128) * 256 + k0 + c8);
        *(uint4*)(&Blds[rb + 192][c8]) = *(const uint4*)(Wt + (long)(rb + 192) * 256 + k0 + c8);

        __syncthreads();

        // prefetch next k-tile of A while MFMA runs
        if (kt < 3) {
            a0 = *(const uint4*)(arow0 + k0 + 64);
            a1 = *(const uint4*)(arow1 + k0 + 64);
        }

#pragma unroll
        for (int ks = 0; ks < 2; ++ks) {
            const int kb = ks * 32 + (lane >> 4) * 8;
            bf16x8 a[4], b[4];
#pragma unroll
            for (int i = 0; i < 4; ++i)
                a[i] = *(const bf16x8*)(&Alds[wm * 64 + i * 16 + (lane & 15)][kb]);
#pragma unroll
            for (int j = 0; j < 4; ++j)
                b[j] = *(const bf16x8*)(&Blds[wn * 64 + j * 16 + (lane & 15)][kb]);
#pragma unroll
            for (int i = 0; i < 4; ++i)
#pragma unroll
                for (int j = 0; j < 4; ++j)
                    acc[i][j] = __builtin_amdgcn_mfma_f32_16x16x32_bf16(a[i], b[j], acc[i][j], 0, 0, 0);
        }

        __syncthreads();
    }

    // ---- epilogue ----
#pragma unroll
    for (int i = 0; i < 4; ++i) {
#pragma unroll
        for (int j = 0; j < 4; ++j) {
            const int lcol = wn * 64 + j * 16 + (lane & 15);
            const float bs = bias[lcol];
            const int col = colOff + lcol;
#pragma unroll
            for (int rj = 0; rj < 4; ++rj) {
                const int row = tm * 128 + wm * 64 + i * 16 + (lane >> 4) * 4 + rj;
                if (row < nrows) {
                    long drow = SCATTER ? (long)dstIdx[row] : (long)row;
                    float val = acc[i][j][rj] + bs;
                    if constexpr (OUT_F32)
                        ((float*)Out)[drow * ldo + col] = val;
                    else
                        ((unsigned short*)Out)[drow * ldo + col] = f2bf(val);
                }
            }
        }
    }
}

// ---------------------------------------------------------------------------
// CSR pooling: one wave per segment s; kv rows for s are [offsets[s],offsets[s+1]).
// score_h = <k[e,h,:], q[s,h,:]>*scale ; ew = exp(score) (shift-free; |score|<~1)
// pooled[s] = sum ew*v / sum ew, written bf16 IN PLACE over q[s].
// ---------------------------------------------------------------------------
__global__ __launch_bounds__(256) void pool_csr_kernel(
    unsigned short* __restrict__ q,          // bf16 [S][256] (in: q, out: pooled)
    const unsigned short* __restrict__ kv,   // bf16 [Msorted][512] (k | v)
    const int* __restrict__ offsets,         // [S+1]
    int S) {
    const int s = blockIdx.x * 4 + (threadIdx.x >> 6);
    if (s >= S) return;
    const int lane = threadIdx.x & 63;
    const int beg = offsets[s];
    const int end = offsets[s + 1];

    const ushort4 qv = *(const ushort4*)(q + (long)s * 256 + lane * 4);
    const float q0 = bf2f(qv.x), q1 = bf2f(qv.y), q2 = bf2f(qv.z), q3 = bf2f(qv.w);

    float a0 = 0.f, a1 = 0.f, a2 = 0.f, a3 = 0.f, denom = 0.f;

    for (int e = beg; e < end; ++e) {
        const ushort4 kk = *(const ushort4*)(kv + (long)e * 512 + lane * 4);
        const ushort4 vv = *(const ushort4*)(kv + (long)e * 512 + 256 + lane * 4);
        float p = q0 * bf2f(kk.x) + q1 * bf2f(kk.y) + q2 * bf2f(kk.z) + q3 * bf2f(kk.w);
        p += __shfl_xor(p, 1);
        p += __shfl_xor(p, 2);
        p += __shfl_xor(p, 4);   // 8-lane head group holds the head dot
        const float ew = expf(p * 0.17677669529663687f);  // 1/sqrt(32)
        a0 += ew * bf2f(vv.x);
        a1 += ew * bf2f(vv.y);
        a2 += ew * bf2f(vv.z);
        a3 += ew * bf2f(vv.w);
        denom += ew;
    }

    const float w = 1.0f / fmaxf(denom, 1e-9f);
    ushort4 o;
    o.x = f2bf(a0 * w);
    o.y = f2bf(a1 * w);
    o.z = f2bf(a2 * w);
    o.w = f2bf(a3 * w);
    *(ushort4*)(q + (long)s * 256 + lane * 4) = o;
}

// ---------------------------------------------------------------------------
extern "C" void kernel_launch(void* const* d_in, const int* in_sizes, int n_in,
                              void* d_out, int out_size, void* d_ws, size_t ws_size,
                              hipStream_t stream) {
    const float* enc  = (const float*)d_in[0];
    const float* W_q  = (const float*)d_in[1];
    const float* b_q  = (const float*)d_in[2];
    const float* W_k  = (const float*)d_in[3];
    const float* b_k  = (const float*)d_in[4];
    const float* W_v  = (const float*)d_in[5];
    const float* b_v  = (const float*)d_in[6];
    const float* W_o  = (const float*)d_in[7];
    const float* b_o  = (const float*)d_in[8];
    const int* map_key = (const int*)d_in[9];    // [M] ast idx
    const int* map_val = (const int*)d_in[10];   // [M] cfg idx (segment id)
    const int* pdg_key = (const int*)d_in[11];   // [S] dst rows (bijection)
    const int* pdg_val = (const int*)d_in[12];   // [S] src ast rows

    const int M = in_sizes[9];
    const int S = in_sizes[11];
    const int NAST = in_sizes[0] / 256;
    const int NB = (S + 255) / 256;

    char* ws = (char*)d_ws;
    size_t off = 0;
    auto alloc = [&](size_t bytes) -> char* {
        char* p = ws + off;
        off += (bytes + 255) & ~(size_t)255;
        return p;
    };

    unsigned short* Wt_q  = (unsigned short*)alloc(256 * 256 * 2);
    unsigned short* Wt_k  = (unsigned short*)alloc(256 * 256 * 2);
    unsigned short* Wt_v  = (unsigned short*)alloc(256 * 256 * 2);
    unsigned short* Wt_o  = (unsigned short*)alloc(256 * 256 * 2);
    int*            counts  = (int*)alloc((size_t)S * 4);
    int*            cursor  = (int*)alloc((size_t)S * 4);
    int*            offsets = (int*)alloc((size_t)(S + 1) * 4);
    int*            bsum    = (int*)alloc((size_t)NB * 4);
    int*            bpref   = (int*)alloc((size_t)NB * 4);
    int*            sorted_src = (int*)alloc((size_t)M * 4);
    unsigned short* enc16 = (unsigned short*)alloc((size_t)NAST * 256 * 2);
    unsigned short* qbuf  = (unsigned short*)alloc((size_t)S * 256 * 2);  // q, then pooled
    unsigned short* kvbuf = (unsigned short*)alloc((size_t)M * 512 * 2);

    // zero counts with a plain kernel (NOT hipMemsetAsync)
    zero_kernel<<<(S + 255) / 256, 256, 0, stream>>>(counts, S);

    conv_enc<<<2048, 256, 0, stream>>>(enc, enc16, NAST * 64);

    convert_weights<<<1024, 256, 0, stream>>>(W_q, W_k, W_v, W_o, Wt_q, Wt_k, Wt_v, Wt_o);

    // counting sort of mapping entries by segment
    hist_kernel<<<(M + 255) / 256, 256, 0, stream>>>(map_val, counts, M);
    scan_p1<<<NB, 256, 0, stream>>>(counts, bsum, S);
    scan_p2<<<1, 256, 0, stream>>>(bsum, bpref, offsets, NB, S);
    scan_p3<<<NB, 256, 0, stream>>>(counts, bpref, offsets, cursor, S);
    scatter_kernel<<<(M + 255) / 256, 256, 0, stream>>>(
        map_key, map_val, cursor, sorted_src, M);

    // Q projection: q[pdg_key[i]] = enc16[pdg_val[i]] @ W_q + b_q
    gemm256<true, true, false><<<(S + 127) / 128, 512, 0, stream>>>(
        enc16, pdg_val, pdg_key, Wt_q, b_q, qbuf, S, 256, 0);

    // K projection into kv[:, 0:256]
    gemm256<true, false, false><<<(M + 127) / 128, 512, 0, stream>>>(
        enc16, sorted_src, nullptr, Wt_k, b_k, kvbuf, M, 512, 0);

    // V projection into kv[:, 256:512]
    gemm256<true, false, false><<<(M + 127) / 128, 512, 0, stream>>>(
        enc16, sorted_src, nullptr, Wt_v, b_v, kvbuf, M, 512, 256);

    // CSR segment softmax + pooling; pooled overwrites qbuf
    pool_csr_kernel<<<(S + 3) / 4, 256, 0, stream>>>(qbuf, kvbuf, offsets, S);

    // output projection to d_out (fp32)
    gemm256<false, false, true><<<(S + 127) / 128, 512, 0, stream>>>(
        qbuf, nullptr, nullptr, Wt_o, b_o, d_out, S, 256, 0);
}